// Round 7
// baseline (499.742 us; speedup 1.0000x reference)
//
#include <hip/hip_runtime.h>

#define NN 200000
#define EE 6400000L
#define NCB 196          // coarse buckets of 1024 nodes
#define CAP 36864        // fixed bucket capacity; mean 32653, sigma 180 -> 23σ margin
#define TILE 8192
#define NTILE 782        // ceil(6400000/8192)
#define QSTRIDE 200064   // quad-table stride in float4 units
#define GB16 12500       // node-groups per phase (16 nodes/group)

__device__ inline void f4add(float4& a, const float4 v) {
    a.x += v.x; a.y += v.y; a.z += v.z; a.w += v.w;
}

// ---------------------------------------------------------------------------
// Edge-index dtype hedge (int64 vs int32): if int64 with values < 2^31, every
// odd 32-bit word is zero. flag=1 -> int64 (word idx = elem<<1), 0 -> int32.
// Also initializes the per-bucket segment cursors gcur[b] = b*CAP.
// ---------------------------------------------------------------------------
__global__ void k_detect(const int* __restrict__ w, int* __restrict__ flag,
                         int* __restrict__ gcur) {
    __shared__ int any;
    if (threadIdx.x == 0) any = 0;
    __syncthreads();
    int found = 0;
    for (int i = threadIdx.x; i < 8192; i += 256)
        if (w[2 * i + 1] != 0) found = 1;
    if (found) atomicOr(&any, 1);
    if (threadIdx.x < NCB) gcur[threadIdx.x] = threadIdx.x * CAP;
    __syncthreads();
    if (threadIdx.x == 0) flag[0] = any ? 0 : 1;
}

// Partition into coarse buckets with tile-exclusive segments (fixed capacity).
// stage entry: src[17:0] | local_dst[27:18]
__global__ __launch_bounds__(256) void k_passA(
    const int* __restrict__ ew, const int* __restrict__ flag,
    int* __restrict__ gcur, unsigned* __restrict__ stage, long e) {
    __shared__ unsigned lv[TILE];
    __shared__ unsigned char lb[TILE];
    __shared__ int lh[NCB], lseg[NCB], lcur[NCB];
    for (int i = threadIdx.x; i < NCB; i += 256) { lh[i] = 0; lcur[i] = 0; }
    __syncthreads();
    long t0 = (long)blockIdx.x * TILE;
    int cnt = (int)min((long)TILE, e - t0);
    int shift = *flag;
    for (int i = threadIdx.x; i < cnt; i += 256) {
        int s = ew[(t0 + i) << shift];
        int d = ew[(EE + t0 + i) << shift];
        int b = d >> 10;
        lv[i] = (unsigned)s | ((unsigned)(d & 1023) << 18);
        lb[i] = (unsigned char)b;
        atomicAdd(&lh[b], 1);
    }
    __syncthreads();
    for (int i = threadIdx.x; i < NCB; i += 256)
        if (lh[i]) lseg[i] = atomicAdd(&gcur[i], lh[i]);
    __syncthreads();
    for (int i = threadIdx.x; i < cnt; i += 256) {
        int b = lb[i];
        int r = atomicAdd(&lcur[b], 1);
        stage[lseg[b] + r] = lv[i];
    }
}

// Per-bucket counting sort: stage (bucket-grouped) -> csr (node-grouped, src).
// Emits offn/degn/dis. Scattered writes stay in the block-owned segment.
__global__ __launch_bounds__(1024) void k_sortB(
    const unsigned* __restrict__ stage, const int* __restrict__ gcur,
    float* __restrict__ dis, int* __restrict__ offn, int* __restrict__ degn,
    unsigned* __restrict__ csr, int n) {
    __shared__ int cnt[1024];
    __shared__ int cur[1024];
    __shared__ int wsum[16];
    int t = threadIdx.x, B = blockIdx.x;
    cnt[t] = 0;
    __syncthreads();
    int s0 = B * CAP, s1 = gcur[B];
    for (int i = s0 + t; i < s1; i += 1024)
        atomicAdd(&cnt[stage[i] >> 18], 1);
    __syncthreads();
    int c = cnt[t];
    int lane = t & 63, w = t >> 6;
    int s = c;
#pragma unroll
    for (int o = 1; o < 64; o <<= 1) {
        int u = __shfl_up(s, o, 64);
        if (lane >= o) s += u;
    }
    if (lane == 63) wsum[w] = s;
    __syncthreads();
    int add = 0;
    for (int k = 0; k < w; ++k) add += wsum[k];
    int excl = s - c + add;
    cur[t] = excl;
    int node = B * 1024 + t;
    if (node < n) {
        offn[node] = s0 + excl;
        degn[node] = c;
        dis[node] = rsqrtf((float)(c + 1));
    }
    __syncthreads();
    for (int i = s0 + t; i < s1; i += 1024) {
        unsigned v = stage[i];
        int pos = s0 + atomicAdd(&cur[v >> 18], 1);
        csr[pos] = v & 0x3FFFF;
    }
}

// Layer 1 matmul: hws = dis ⊙ (x @ W1), written QUAD-MAJOR:
// out[q*QSTRIDE + node] = float4(acc[4q..4q+3]) * dv
__global__ __launch_bounds__(256) void k_mm1(
    const float* __restrict__ x, const float* __restrict__ W,
    const float* __restrict__ dis, float4* __restrict__ outq, int n) {
    __shared__ float Wl[256 * 16];
    int t = threadIdx.x;
#pragma unroll
    for (int i = 0; i < 4; ++i)
        ((float4*)Wl)[t + i * 256] = ((const float4*)W)[t + i * 256];
    __syncthreads();

    int node = blockIdx.x * 256 + t;
    if (node >= n) return;

    const float4* xr = (const float4*)(x + (long)node * 256);
    float acc[16];
#pragma unroll
    for (int o = 0; o < 16; ++o) acc[o] = 0.f;

#pragma unroll 8
    for (int kk = 0; kk < 64; ++kk) {
        float4 xv = xr[kk];
#pragma unroll
        for (int q = 0; q < 4; ++q) {
            float xs = (q == 0) ? xv.x : (q == 1) ? xv.y : (q == 2) ? xv.z : xv.w;
            const float4* wr = (const float4*)&Wl[(kk * 4 + q) * 16];
#pragma unroll
            for (int oo = 0; oo < 4; ++oo) {
                float4 wv = wr[oo];
                acc[oo * 4 + 0] = fmaf(xs, wv.x, acc[oo * 4 + 0]);
                acc[oo * 4 + 1] = fmaf(xs, wv.y, acc[oo * 4 + 1]);
                acc[oo * 4 + 2] = fmaf(xs, wv.z, acc[oo * 4 + 2]);
                acc[oo * 4 + 3] = fmaf(xs, wv.w, acc[oo * 4 + 3]);
            }
        }
    }
    float dv = dis[node];
#pragma unroll
    for (int q = 0; q < 4; ++q)
        outq[q * QSTRIDE + node] = make_float4(acc[q * 4] * dv, acc[q * 4 + 1] * dv,
                                               acc[q * 4 + 2] * dv, acc[q * 4 + 3] * dv);
}

// 16x16 matmul: hws = dis ⊙ (h @ W), quad-major in AND out.
__global__ __launch_bounds__(256) void k_mm2(
    const float4* __restrict__ hq, const float* __restrict__ W,
    const float* __restrict__ dis, float4* __restrict__ outq, int n) {
    __shared__ float Wl[256];
    if (threadIdx.x < 64) ((float4*)Wl)[threadIdx.x] = ((const float4*)W)[threadIdx.x];
    __syncthreads();
    int node = blockIdx.x * 256 + threadIdx.x;
    if (node >= n) return;
    float hv[16];
#pragma unroll
    for (int i = 0; i < 4; ++i) {
        float4 v = hq[i * QSTRIDE + node];
        hv[i * 4 + 0] = v.x; hv[i * 4 + 1] = v.y; hv[i * 4 + 2] = v.z; hv[i * 4 + 3] = v.w;
    }
    float acc[16];
#pragma unroll
    for (int o = 0; o < 16; ++o) acc[o] = 0.f;
#pragma unroll
    for (int k = 0; k < 16; ++k) {
        float xs = hv[k];
#pragma unroll
        for (int o = 0; o < 16; ++o) acc[o] = fmaf(xs, Wl[k * 16 + o], acc[o]);
    }
    float dv = dis[node];
#pragma unroll
    for (int q = 0; q < 4; ++q)
        outq[q * QSTRIDE + node] = make_float4(acc[q * 4] * dv, acc[q * 4 + 1] * dv,
                                               acc[q * 4 + 2] * dv, acc[q * 4 + 3] * dv);
}

// 16x1 matmul: hws3 = dis ⊙ (h @ W3), quad-major in, scalar out.
__global__ __launch_bounds__(256) void k_mm3(
    const float4* __restrict__ hq, const float* __restrict__ W,
    const float* __restrict__ dis, float* __restrict__ hws3, int n) {
    int node = blockIdx.x * 256 + threadIdx.x;
    if (node >= n) return;
    float acc = 0.f;
#pragma unroll
    for (int i = 0; i < 4; ++i) {
        float4 v = hq[i * QSTRIDE + node];
        acc = fmaf(v.x, W[i * 4 + 0], acc);
        acc = fmaf(v.y, W[i * 4 + 1], acc);
        acc = fmaf(v.z, W[i * 4 + 2], acc);
        acc = fmaf(v.w, W[i * 4 + 3], acc);
    }
    hws3[node] = acc * dis[node];
}

// Quad-phased gather-aggregate. Grid = 4 phases x GB16 groups; phase q gathers
// ONLY from the 3.2MB quad-q table (L2-resident). Block = 16 nodes x 16 lanes;
// lanes stride the edge list (coalesced csr), shfl-xor reduce, lane 0 epilogue:
// h_q[node] = relu?( b_q + dv*( sum_e tab_q[src_e] + tab_q[node] ) )
template <int RELU>
__global__ __launch_bounds__(256) void k_g16p(
    const int* __restrict__ offn, const int* __restrict__ degn,
    const unsigned* __restrict__ csr, const float* __restrict__ dis,
    const float4* __restrict__ tabq, const float* __restrict__ b,
    float4* __restrict__ outq, int n) {
    int bid = blockIdx.x;
    int q = bid / GB16;                 // phase-major: same-q blocks dispatch together
    int g = bid - q * GB16;
    int t = threadIdx.x;
    int node = g * 16 + (t >> 4);
    int ln = t & 15;
    if (node >= n) return;
    const float4* tab = tabq + (long)q * QSTRIDE;
    int s0 = offn[node], dg = degn[node];
    float4 a0 = make_float4(0.f, 0.f, 0.f, 0.f);
    float4 a1 = make_float4(0.f, 0.f, 0.f, 0.f);
    int k = ln;
    for (; k + 16 < dg; k += 32) {
        f4add(a0, tab[csr[s0 + k]]);
        f4add(a1, tab[csr[s0 + k + 16]]);
    }
    if (k < dg) f4add(a0, tab[csr[s0 + k]]);
    f4add(a0, a1);
#pragma unroll
    for (int o = 8; o >= 1; o >>= 1) {
        a0.x += __shfl_xor(a0.x, o, 16);
        a0.y += __shfl_xor(a0.y, o, 16);
        a0.z += __shfl_xor(a0.z, o, 16);
        a0.w += __shfl_xor(a0.w, o, 16);
    }
    if (ln == 0) {
        f4add(a0, tab[node]);           // self-loop (pre-scaled)
        float dv = dis[node];
        float4 bb = ((const float4*)b)[q];
        float4 r = make_float4(fmaf(dv, a0.x, bb.x), fmaf(dv, a0.y, bb.y),
                               fmaf(dv, a0.z, bb.z), fmaf(dv, a0.w, bb.w));
        if (RELU) {
            r.x = fmaxf(r.x, 0.f); r.y = fmaxf(r.y, 0.f);
            r.z = fmaxf(r.z, 0.f); r.w = fmaxf(r.w, 0.f);
        }
        outq[(long)q * QSTRIDE + node] = r;
    }
}

// Gather-aggregate, 1 channel from the 800KB pre-scaled table (L2-resident).
__global__ __launch_bounds__(256) void k_g1(
    const int* __restrict__ offn, const int* __restrict__ degn,
    const unsigned* __restrict__ csr, const float* __restrict__ dis,
    const float* __restrict__ hws3, const float* __restrict__ b,
    float* __restrict__ out, int n) {
    int t = threadIdx.x;
    int node = blockIdx.x * 16 + (t >> 4);
    int ln = t & 15;
    if (node >= n) return;
    int s0 = offn[node], dg = degn[node];
    float acc = 0.f;
    for (int k = ln; k < dg; k += 16)
        acc += hws3[csr[s0 + k]];
#pragma unroll
    for (int o = 8; o >= 1; o >>= 1) acc += __shfl_down(acc, o, 16);
    if (ln == 0)
        out[node] = fmaf(dis[node], acc + hws3[node], b[0]);
}

extern "C" void kernel_launch(void* const* d_in, const int* in_sizes, int n_in,
                              void* d_out, int out_size, void* d_ws, size_t ws_size,
                              hipStream_t stream) {
    const float* x  = (const float*)d_in[0];
    const int*   ew = (const int*)d_in[1];
    const float* W1 = (const float*)d_in[2];
    const float* b1 = (const float*)d_in[3];
    const float* W2 = (const float*)d_in[4];
    const float* b2 = (const float*)d_in[5];
    const float* W3 = (const float*)d_in[6];
    const float* b3 = (const float*)d_in[7];
    float* out = (float*)d_out;

    // Workspace (4-byte words), ~87 MB. bufA/bufB are quad-major float4 tables.
    unsigned* stage = (unsigned*)d_ws;               // NCB*CAP = 7,225,344
    unsigned* csr   = stage + (long)NCB * CAP;       // 7,225,344
    int*      gcur  = (int*)(csr + (long)NCB * CAP); // 256
    int*      flag  = gcur + 256;                    // 16
    int*      offn  = flag + 16;                     // 200,704
    int*      degn  = offn + 200704;                 // 200,704
    float*    dis   = (float*)(degn + 200704);       // 200,704
    float4*   bufA  = (float4*)(dis + 200704);       // 4*QSTRIDE float4 (hws / +hws3)
    float4*   bufB  = bufA + 4 * QSTRIDE;            // 4*QSTRIDE float4 (h)

    const int n = NN;
    const long e = EE;
    int nb = (n + 255) / 256;   // 782
    int g1b = (n + 15) / 16;    // 12500

    // detect + cursor init -> partition -> per-bucket sort
    k_detect<<<1, 256, 0, stream>>>(ew, flag, gcur);
    k_passA<<<NTILE, 256, 0, stream>>>(ew, flag, gcur, stage, e);
    k_sortB<<<NCB, 1024, 0, stream>>>(stage, gcur, dis, offn, degn, csr, n);

    // Layer 1
    k_mm1<<<nb, 256, 0, stream>>>(x, W1, dis, bufA, n);
    k_g16p<1><<<4 * GB16, 256, 0, stream>>>(offn, degn, csr, dis, bufA, b1, bufB, n);
    // Layer 2
    k_mm2<<<nb, 256, 0, stream>>>(bufB, W2, dis, bufA, n);
    k_g16p<1><<<4 * GB16, 256, 0, stream>>>(offn, degn, csr, dis, bufA, b2, bufB, n);
    // Layer 3
    k_mm3<<<nb, 256, 0, stream>>>(bufB, W3, dis, (float*)bufA, n);
    k_g1<<<g1b, 256, 0, stream>>>(offn, degn, csr, dis, (const float*)bufA, b3, out, n);
}